// Round 4
// baseline (995.242 us; speedup 1.0000x reference)
//
#include <hip/hip_runtime.h>
#include <hip/hip_bf16.h>
#include <stdint.h>

#define T_TOK 2048
#define H_DIM 2048
#define E_NUM 16
#define I_DIM 768

typedef __bf16 bf16;
typedef __bf16 bf16x4 __attribute__((ext_vector_type(4)));
typedef __bf16 bf16x8 __attribute__((ext_vector_type(8)));
typedef float f32x4 __attribute__((ext_vector_type(4)));

__device__ __forceinline__ void async_cp16(void* l, const void* g) {
    __builtin_amdgcn_global_load_lds(
        (const __attribute__((address_space(1))) void*)g,
        (__attribute__((address_space(3))) void*)l, 16, 0, 0);
}

// ---------------- Router: fp64 logits, LDS 2-level reduce, top-2, x->bf16 ----
__global__ __launch_bounds__(256) void router_kernel(
    const float* __restrict__ x, const float* __restrict__ gw,
    float* __restrict__ logits, int* __restrict__ cnt,
    int* __restrict__ tok_list, float* __restrict__ wgt_list,
    bf16* __restrict__ xb)
{
    const int t = blockIdx.x;
    const int tid = threadIdx.x;

    double part[E_NUM];
#pragma unroll
    for (int e = 0; e < E_NUM; ++e) part[e] = 0.0;

#pragma unroll
    for (int it = 0; it < 2; ++it) {
        int h = it * 1024 + tid * 4;
        float4 xv = *(const float4*)(x + (size_t)t * H_DIM + h);
        bf16x4 xb4 = { (bf16)xv.x, (bf16)xv.y, (bf16)xv.z, (bf16)xv.w };
        *(bf16x4*)(xb + (size_t)t * H_DIM + h) = xb4;
#pragma unroll
        for (int e = 0; e < E_NUM; ++e) {
            float4 wv = *(const float4*)(gw + (size_t)e * H_DIM + h);
            part[e] += (double)xv.x * (double)wv.x + (double)xv.y * (double)wv.y
                     + (double)xv.z * (double)wv.z + (double)xv.w * (double)wv.w;
        }
    }

    __shared__ double red[E_NUM][256];
    __shared__ double red2[E_NUM][16];
    __shared__ float lg[E_NUM];
#pragma unroll
    for (int e = 0; e < E_NUM; ++e) red[e][tid] = part[e];
    __syncthreads();
    {
        int e = tid >> 4, seg = tid & 15;
        double s = 0.0;
#pragma unroll
        for (int j = 0; j < 16; ++j) s += red[e][seg * 16 + j];
        red2[e][seg] = s;
    }
    __syncthreads();
    if (tid < E_NUM) {
        double s = 0.0;
#pragma unroll
        for (int j = 0; j < 16; ++j) s += red2[tid][j];
        float v = (float)s;
        lg[tid] = v;
        logits[(size_t)t * E_NUM + tid] = v;
    }
    __syncthreads();
    if (tid == 0) {
        int i0 = 0; float v0 = lg[0];
#pragma unroll
        for (int e = 1; e < E_NUM; ++e) if (lg[e] > v0) { v0 = lg[e]; i0 = e; }
        int i1 = -1; float v1 = -3.4e38f;
#pragma unroll
        for (int e = 0; e < E_NUM; ++e) if (e != i0 && lg[e] > v1) { v1 = lg[e]; i1 = e; }
        float w0 = 1.0f / (1.0f + __expf(v1 - v0));
        float w1 = 1.0f - w0;
        int p0 = atomicAdd(&cnt[i0], 1);
        tok_list[i0 * T_TOK + p0] = t; wgt_list[i0 * T_TOK + p0] = w0;
        int p1 = atomicAdd(&cnt[i1], 1);
        tok_list[i1 * T_TOK + p1] = t; wgt_list[i1 * T_TOK + p1] = w1;
    }
}

// ---------------- Offsets scan (16 values) ----------------------------------
__global__ void scan_kernel(const int* __restrict__ cnt, int* __restrict__ offs)
{
    if (threadIdx.x == 0) {
        int o = 0;
        for (int e = 0; e < E_NUM; ++e) { offs[e] = o; o += cnt[e]; }
    }
}

// ---------------- Grouped gate_up GEMM + SwiGLU ------------------------------
// M=128 tokens x 64 i-cols (128 weight rows: 64 g then 64 u). A bf16, B fp32
// staged raw via global_load_lds, cvt at fragment build. XOR-swizzled chunks.
__global__ __launch_bounds__(256, 3) void gateup_kernel(
    const bf16* __restrict__ xb, const float* __restrict__ gup,
    const int* __restrict__ cnt, const int* __restrict__ offs,
    const int* __restrict__ tok_list, bf16* __restrict__ hbuf)
{
    const int e = blockIdx.z;
    const int count = cnt[e];
    const int row0 = blockIdx.x * 128;      // x fastest: row-sharers adjacent
    if (row0 >= count) return;
    const int i0 = blockIdx.y * 64;
    const int hoff = offs[e];
    const int tid = threadIdx.x;
    const int lane = tid & 63, wid = tid >> 6;

    __shared__ __align__(16) bf16 As[128 * 64];    // 16 KB, 8 chunks/row, mask &7
    __shared__ __align__(16) float Bs[128 * 64];   // 32 KB, 16 chunks/row, mask &15

    // A staging: 1024 chunks, 4/thread
    const bf16* srcA[4]; bf16* dstA[4];
#pragma unroll
    for (int i = 0; i < 4; ++i) {
        int idx = i * 256 + tid;
        int r = idx >> 3, s = idx & 7;
        int c = s ^ (r & 7);
        int tr = row0 + r; if (tr >= count) tr = count - 1;
        srcA[i] = xb + (size_t)tok_list[e * T_TOK + tr] * H_DIM + c * 8;
        dstA[i] = As + (size_t)(i * 256 + wid * 64) * 8;
    }
    // B staging: 2048 chunks, 8/thread; rows 0..63 g, 64..127 u
    const float* srcB[8]; float* dstB[8];
#pragma unroll
    for (int i = 0; i < 8; ++i) {
        int idx = i * 256 + tid;
        int r = idx >> 4, s = idx & 15;
        int c = s ^ (r & 15);
        size_t grow = (size_t)e * (2 * I_DIM) + ((r >> 6) ? I_DIM : 0) + i0 + (r & 63);
        srcB[i] = gup + grow * H_DIM + c * 4;
        dstB[i] = Bs + (size_t)(i * 256 + wid * 64) * 4;
    }

    f32x4 acc[2][8];
#pragma unroll
    for (int a = 0; a < 2; ++a)
#pragma unroll
        for (int b = 0; b < 8; ++b) acc[a][b] = (f32x4){0.f, 0.f, 0.f, 0.f};

    const int la = lane & 15, lq = lane >> 4;

    for (int k0 = 0; k0 < H_DIM; k0 += 64) {
#pragma unroll
        for (int i = 0; i < 4; ++i) async_cp16(dstA[i], srcA[i] + k0);
#pragma unroll
        for (int i = 0; i < 8; ++i) async_cp16(dstB[i], srcB[i] + k0);
        __syncthreads();
#pragma unroll
        for (int ks = 0; ks < 2; ++ks) {
            int chA = ks * 4 + lq;
            int c0 = ks * 8 + lq * 2;
            bf16x8 af[2], bfr[8];
#pragma unroll
            for (int mt = 0; mt < 2; ++mt) {
                int row = 32 * wid + 16 * mt + la;
                int sl = chA ^ (row & 7);
                af[mt] = *(const bf16x8*)(As + (size_t)(row * 8 + sl) * 8);
            }
#pragma unroll
            for (int nt = 0; nt < 8; ++nt) {
                int row = 16 * nt + la;
                int s0 = c0 ^ (row & 15);
                f32x4 v0 = *(const f32x4*)(Bs + (size_t)(row * 16 + s0) * 4);
                f32x4 v1 = *(const f32x4*)(Bs + (size_t)(row * 16 + (s0 ^ 1)) * 4);
                bfr[nt] = (bf16x8){ (bf16)v0.x, (bf16)v0.y, (bf16)v0.z, (bf16)v0.w,
                                    (bf16)v1.x, (bf16)v1.y, (bf16)v1.z, (bf16)v1.w };
            }
#pragma unroll
            for (int mt = 0; mt < 2; ++mt)
#pragma unroll
                for (int nt = 0; nt < 8; ++nt)
                    acc[mt][nt] = __builtin_amdgcn_mfma_f32_16x16x32_bf16(af[mt], bfr[nt], acc[mt][nt], 0, 0, 0);
        }
        __syncthreads();
    }

    // epilogue: nt = g, nt+4 = u, col = i0 + 16*nt + la
#pragma unroll
    for (int mt = 0; mt < 2; ++mt)
#pragma unroll
        for (int nt = 0; nt < 4; ++nt)
#pragma unroll
            for (int r = 0; r < 4; ++r) {
                int trow = 32 * wid + 16 * mt + lq * 4 + r;
                if (row0 + trow < count) {
                    float g = acc[mt][nt][r], u = acc[mt][nt + 4][r];
                    float hv = (g / (1.0f + __expf(-g))) * u;
                    int col = i0 + 16 * nt + la;
                    hbuf[(size_t)(hoff + row0 + trow) * I_DIM + col] = (bf16)hv;
                }
            }
}

// ---------------- Grouped down GEMM + weighted scatter -----------------------
// M=128 tokens x N=128 H-cols, K=768.
__global__ __launch_bounds__(256, 3) void down_kernel(
    const float* __restrict__ dw, const bf16* __restrict__ hbuf,
    const int* __restrict__ cnt, const int* __restrict__ offs,
    const int* __restrict__ tok_list, const float* __restrict__ wgt_list,
    float* __restrict__ out)
{
    const int e = blockIdx.z;
    const int count = cnt[e];
    const int row0 = blockIdx.x * 128;
    if (row0 >= count) return;
    const int n0 = blockIdx.y * 128;
    const int hoff = offs[e];
    const int tid = threadIdx.x;
    const int lane = tid & 63, wid = tid >> 6;

    __shared__ __align__(16) bf16 As[128 * 64];
    __shared__ __align__(16) float Bs[128 * 64];

    const bf16* srcA[4]; bf16* dstA[4];
#pragma unroll
    for (int i = 0; i < 4; ++i) {
        int idx = i * 256 + tid;
        int r = idx >> 3, s = idx & 7;
        int c = s ^ (r & 7);
        int tr = row0 + r; if (tr >= count) tr = count - 1;
        srcA[i] = hbuf + (size_t)(hoff + tr) * I_DIM + c * 8;
        dstA[i] = As + (size_t)(i * 256 + wid * 64) * 8;
    }
    const float* srcB[8]; float* dstB[8];
#pragma unroll
    for (int i = 0; i < 8; ++i) {
        int idx = i * 256 + tid;
        int r = idx >> 4, s = idx & 15;
        int c = s ^ (r & 15);
        srcB[i] = dw + ((size_t)e * H_DIM + n0 + r) * I_DIM + c * 4;
        dstB[i] = Bs + (size_t)(i * 256 + wid * 64) * 4;
    }

    f32x4 acc[2][8];
#pragma unroll
    for (int a = 0; a < 2; ++a)
#pragma unroll
        for (int b = 0; b < 8; ++b) acc[a][b] = (f32x4){0.f, 0.f, 0.f, 0.f};

    const int la = lane & 15, lq = lane >> 4;

    for (int k0 = 0; k0 < I_DIM; k0 += 64) {
#pragma unroll
        for (int i = 0; i < 4; ++i) async_cp16(dstA[i], srcA[i] + k0);
#pragma unroll
        for (int i = 0; i < 8; ++i) async_cp16(dstB[i], srcB[i] + k0);
        __syncthreads();
#pragma unroll
        for (int ks = 0; ks < 2; ++ks) {
            int chA = ks * 4 + lq;
            int c0 = ks * 8 + lq * 2;
            bf16x8 af[2], bfr[8];
#pragma unroll
            for (int mt = 0; mt < 2; ++mt) {
                int row = 32 * wid + 16 * mt + la;
                int sl = chA ^ (row & 7);
                af[mt] = *(const bf16x8*)(As + (size_t)(row * 8 + sl) * 8);
            }
#pragma unroll
            for (int nt = 0; nt < 8; ++nt) {
                int row = 16 * nt + la;
                int s0 = c0 ^ (row & 15);
                f32x4 v0 = *(const f32x4*)(Bs + (size_t)(row * 16 + s0) * 4);
                f32x4 v1 = *(const f32x4*)(Bs + (size_t)(row * 16 + (s0 ^ 1)) * 4);
                bfr[nt] = (bf16x8){ (bf16)v0.x, (bf16)v0.y, (bf16)v0.z, (bf16)v0.w,
                                    (bf16)v1.x, (bf16)v1.y, (bf16)v1.z, (bf16)v1.w };
            }
#pragma unroll
            for (int mt = 0; mt < 2; ++mt)
#pragma unroll
                for (int nt = 0; nt < 8; ++nt)
                    acc[mt][nt] = __builtin_amdgcn_mfma_f32_16x16x32_bf16(af[mt], bfr[nt], acc[mt][nt], 0, 0, 0);
        }
        __syncthreads();
    }

#pragma unroll
    for (int mt = 0; mt < 2; ++mt)
#pragma unroll
        for (int nt = 0; nt < 8; ++nt)
#pragma unroll
            for (int r = 0; r < 4; ++r) {
                int trow = 32 * wid + 16 * mt + lq * 4 + r;
                if (row0 + trow < count) {
                    int col = n0 + 16 * nt + la;
                    int grow = row0 + trow;
                    atomicAdd(&out[(size_t)tok_list[e * T_TOK + grow] * H_DIM + col],
                              wgt_list[e * T_TOK + grow] * acc[mt][nt][r]);
                }
            }
}

// ---------------- Launch -----------------------------------------------------
extern "C" void kernel_launch(void* const* d_in, const int* in_sizes, int n_in,
                              void* d_out, int out_size, void* d_ws, size_t ws_size,
                              hipStream_t stream)
{
    const float* x   = (const float*)d_in[0];
    const float* gw  = (const float*)d_in[1];
    const float* gup = (const float*)d_in[2];
    const float* dw  = (const float*)d_in[3];
    float* out = (float*)d_out;
    float* logits = out + (size_t)T_TOK * H_DIM;

    char* ws = (char*)d_ws;
    int*   cnt      = (int*)(ws + 0);
    int*   offs     = (int*)(ws + 256);
    int*   tok_list = (int*)(ws + 512);                 // 128 KiB
    float* wgt_list = (float*)(ws + 131584);            // 128 KiB
    bf16*  hbuf     = (bf16*)(ws + 262656);             // 6 MiB
    bf16*  xb       = (bf16*)(ws + 6554112);            // 8 MiB (end ~14.3 MiB)

    hipMemsetAsync(cnt, 0, 256, stream);
    hipMemsetAsync(out, 0, (size_t)T_TOK * H_DIM * sizeof(float), stream);

    router_kernel<<<T_TOK, 256, 0, stream>>>(x, gw, logits, cnt, tok_list, wgt_list, xb);
    scan_kernel<<<1, 64, 0, stream>>>(cnt, offs);
    gateup_kernel<<<dim3(T_TOK / 128, I_DIM / 64, E_NUM), 256, 0, stream>>>(
        xb, gup, cnt, offs, tok_list, hbuf);
    down_kernel<<<dim3(T_TOK / 128, H_DIM / 128, E_NUM), 256, 0, stream>>>(
        dw, hbuf, cnt, offs, tok_list, wgt_list, out);
}